// Round 1
// baseline (746.404 us; speedup 1.0000x reference)
//
#include <hip/hip_runtime.h>
#include <math.h>

#define N_NODES 50000
#define CDIM    256
#define NHEAD   8
#define DHEAD   32
#define DEG     16

// ---------------------------------------------------------------------------
// Kernel A: Q,K,V = h @ {Wq,Wk,Wv}.  f32 vector GEMM (no fp32 MFMA on CDNA4).
// Block: 512 threads, 32 rows x 256 cols, 4x4 register tile per thread.
// h tile staged transposed in LDS (pitch 36 floats -> 16B-aligned float4 reads).
// ---------------------------------------------------------------------------
#define ROWS 32

__global__ __launch_bounds__(512) void qkv_gemm(
    const float* __restrict__ h,
    const float* __restrict__ Wq, const float* __restrict__ Wk,
    const float* __restrict__ Wv,
    float* __restrict__ Q, float* __restrict__ K, float* __restrict__ V)
{
    __shared__ __align__(16) float hT[CDIM][36];   // [k][row], padded pitch

    const int block_row = blockIdx.x * ROWS;
    const int tid = threadIdx.x;

    // stage h tile transposed: 32 rows x 256 cols = 8192 floats, 16 per thread
#pragma unroll
    for (int i = 0; i < 16; ++i) {
        int idx = i * 512 + tid;
        int r = idx >> 8;          // 0..31
        int c = idx & 255;         // 0..255
        int gr = block_row + r;
        float v = (gr < N_NODES) ? h[gr * CDIM + c] : 0.f;
        hT[c][r] = v;
    }
    __syncthreads();

    const int tx = tid & 63;       // 64 column groups
    const int ty = tid >> 6;       // 8 row groups
    const int c0 = tx * 4;
    const int r0 = ty * 4;

    const float* Ws[3] = {Wq, Wk, Wv};
    float*       Os[3] = {Q, K, V};

#pragma unroll
    for (int m = 0; m < 3; ++m) {
        const float* __restrict__ W = Ws[m];
        float acc[4][4];
#pragma unroll
        for (int j = 0; j < 4; ++j)
#pragma unroll
            for (int i = 0; i < 4; ++i) acc[j][i] = 0.f;

#pragma unroll 4
        for (int k = 0; k < CDIM; ++k) {
            float4 wv = *(const float4*)(W + k * CDIM + c0);
            float4 hv = *(const float4*)(&hT[k][r0]);
            float hvv[4] = {hv.x, hv.y, hv.z, hv.w};
            float wvv[4] = {wv.x, wv.y, wv.z, wv.w};
#pragma unroll
            for (int j = 0; j < 4; ++j)
#pragma unroll
                for (int i = 0; i < 4; ++i)
                    acc[j][i] += hvv[j] * wvv[i];
        }

        float* __restrict__ O = Os[m];
#pragma unroll
        for (int j = 0; j < 4; ++j) {
            int gr = block_row + r0 + j;
            if (gr < N_NODES) {
                float4 o;
                o.x = acc[j][0]; o.y = acc[j][1];
                o.z = acc[j][2]; o.w = acc[j][3];
                *(float4*)(O + gr * CDIM + c0) = o;
            }
        }
    }
}

// ---------------------------------------------------------------------------
// Kernel B: 2D RoPE applied in-place to Q and K.
// One thread per (node, head, pair): 50000 * 8 * 16 = 6.4M threads.
// k<8 -> x-half (dims [k, k+8]); k>=8 -> y-half (dims [16+kk, 24+kk]).
// inv_freq[j] = 10000^(-j/8) = 10^(-j/2).
// ---------------------------------------------------------------------------
__global__ __launch_bounds__(256) void rope_kernel(
    const float* __restrict__ pos,
    float* __restrict__ Q, float* __restrict__ K)
{
    int gid = blockIdx.x * blockDim.x + threadIdx.x;
    if (gid >= N_NODES * NHEAD * 16) return;
    int n    = gid >> 7;
    int r    = gid & 127;
    int head = r >> 4;
    int k    = r & 15;
    int j    = k & 7;

    float coord;
    int a;
    if (k < 8) {
        coord = pos[n * 2 + 0];
        a = head * DHEAD + j;
    } else {
        coord = pos[n * 2 + 1];
        a = head * DHEAD + 16 + j;
    }
    // inv_freq = 10^(-j/2) = exp2(-j * 0.5 * log2(10))
    float inv_freq = exp2f(-(float)j * 1.660964047443681f);
    float angle = coord * 64.f * inv_freq;
    float s, c;
    sincosf(angle, &s, &c);

    int b = a + 8;
    int base = n * CDIM;
    float qa = Q[base + a], qb = Q[base + b];
    Q[base + a] = qa * c - qb * s;
    Q[base + b] = qb * c + qa * s;
    float ka = K[base + a], kb = K[base + b];
    K[base + a] = ka * c - kb * s;
    K[base + b] = kb * c + ka * s;
}

// ---------------------------------------------------------------------------
// Kernel C: edge attention + segment reduce.
// dst = repeat(arange(N), DEG): node i's incoming edges are [16i, 16i+16),
// all with the same dst.  One 256-thread block per node: head = tid>>5,
// dim = tid&31.  Dot product via 32-lane shfl_xor butterfly.
// ---------------------------------------------------------------------------
__global__ __launch_bounds__(256) void edge_attn(
    const float* __restrict__ Q, const float* __restrict__ K,
    const float* __restrict__ V,
    const int* __restrict__ src, const int* __restrict__ dst,
    float* __restrict__ out)
{
    const int n   = blockIdx.x;
    const int tid = threadIdx.x;
    const int eb  = n * DEG;

    const int orow = dst[eb];                 // uniform across block
    const float q  = Q[orow * CDIM + tid];

    float acc = 0.f, z = 0.f;
#pragma unroll
    for (int j = 0; j < DEG; ++j) {
        int s = src[eb + j];                  // uniform
        float kv = K[s * CDIM + tid];
        float p = q * kv;
        p += __shfl_xor(p, 16);
        p += __shfl_xor(p, 8);
        p += __shfl_xor(p, 4);
        p += __shfl_xor(p, 2);
        p += __shfl_xor(p, 1);
        float sc = __expf(fminf(fmaxf(p * 0.17677669529663687f, -5.f), 5.f));
        float vv = V[s * CDIM + tid];
        acc += sc * vv;
        z   += sc;
    }
    out[orow * CDIM + tid] = acc / z;
}

// ---------------------------------------------------------------------------
extern "C" void kernel_launch(void* const* d_in, const int* in_sizes, int n_in,
                              void* d_out, int out_size, void* d_ws, size_t ws_size,
                              hipStream_t stream)
{
    const float* h   = (const float*)d_in[0];
    const float* pos = (const float*)d_in[1];
    const float* Wq  = (const float*)d_in[2];
    const float* Wk  = (const float*)d_in[3];
    const float* Wv  = (const float*)d_in[4];
    const int*   src = (const int*)d_in[5];
    const int*   dst = (const int*)d_in[6];
    float* out = (float*)d_out;

    float* Q = (float*)d_ws;
    float* K = Q + (size_t)N_NODES * CDIM;
    float* V = K + (size_t)N_NODES * CDIM;

    qkv_gemm<<<(N_NODES + ROWS - 1) / ROWS, 512, 0, stream>>>(h, Wq, Wk, Wv, Q, K, V);
    rope_kernel<<<(N_NODES * NHEAD * 16 + 255) / 256, 256, 0, stream>>>(pos, Q, K);
    edge_attn<<<N_NODES, 256, 0, stream>>>(Q, K, V, src, dst, out);
}

// Round 2
// 293.948 us; speedup vs baseline: 2.5392x; 2.5392x over previous
//
#include <hip/hip_runtime.h>
#include <math.h>
#include <stdint.h>

#define NN   50000
#define NPAD 50048          // 391 * 128
#define CD   256
#define DEG  16

typedef _Float16 f16;
typedef _Float16 f16x2 __attribute__((ext_vector_type(2)));
typedef _Float16 f16x8 __attribute__((ext_vector_type(8)));
typedef float    f32x4 __attribute__((ext_vector_type(4)));

typedef const uint32_t __attribute__((address_space(1)))* gptr_t;
typedef uint32_t       __attribute__((address_space(3)))* lptr_t;

// ---------------------------------------------------------------------------
// h (f32) -> h16 (f16), zero-padded rows up to NPAD
// ---------------------------------------------------------------------------
__global__ __launch_bounds__(256) void conv_h(const float* __restrict__ h,
                                              f16* __restrict__ o)
{
    size_t i8 = ((size_t)blockIdx.x * 256 + threadIdx.x) * 8;
    if (i8 >= (size_t)NPAD * CD) return;
    f16x8 r;
    if (i8 < (size_t)NN * CD) {
        float4 a = ((const float4*)(h + i8))[0];
        float4 b = ((const float4*)(h + i8))[1];
        r[0] = (f16)a.x; r[1] = (f16)a.y; r[2] = (f16)a.z; r[3] = (f16)a.w;
        r[4] = (f16)b.x; r[5] = (f16)b.y; r[6] = (f16)b.z; r[7] = (f16)b.w;
    } else {
        r = (f16x8)(f16)0.f;
    }
    *(f16x8*)(o + i8) = r;
}

// ---------------------------------------------------------------------------
// W (f32 [k][n]) -> Wt (f16 [n][k]) for each of the 3 matrices
// ---------------------------------------------------------------------------
__global__ __launch_bounds__(256) void conv_w(const float* __restrict__ Wq,
                                              const float* __restrict__ Wk,
                                              const float* __restrict__ Wv,
                                              f16* __restrict__ Wt)
{
    const float* W = (blockIdx.y == 0) ? Wq : (blockIdx.y == 1) ? Wk : Wv;
    int n = blockIdx.x, k = threadIdx.x;
    Wt[(size_t)blockIdx.y * 65536 + n * 256 + k] = (f16)W[k * 256 + n];
}

// ---------------------------------------------------------------------------
// Q|K|V = h16 @ W   via mfma_f32_16x16x32_f16.
// Block 256 thr (4 waves), tile 128(M) x 128(N), BK=64, K=256 -> 4 steps.
// LDS: A[128r][64k] f16 + B[128n][64k] f16, 16 KB each, XOR slot swizzle
// (slot' = slot ^ (row&7)) applied via pre-swizzled global source for
// global_load_lds (linear dest) and on the ds_read side.
// grid: (391, 2, 3)  z selects matrix, y selects N-half.
// ---------------------------------------------------------------------------
__global__ __launch_bounds__(256) void gemm16(
    const f16* __restrict__ h16, const f16* __restrict__ Wt,
    f16* __restrict__ Qo, f16* __restrict__ Ko, f16* __restrict__ Vo)
{
    __shared__ __align__(16) char lds[32768];   // A: [0,16K) B: [16K,32K)

    const int t    = threadIdx.x;
    const int lane = t & 63;
    const int wid  = t >> 6;
    const int tm   = blockIdx.x;
    const int nc0  = blockIdx.y * 128;
    const int z    = blockIdx.z;

    const f16* B = Wt + (size_t)z * 65536;
    f16* O = (z == 0) ? Qo : (z == 1) ? Ko : Vo;

    const int r15 = lane & 15;
    const int g4  = lane >> 4;
    const int l7  = lane & 7;
    const int wm  = (wid >> 1) * 64;
    const int wn  = (wid & 1) * 64;

    f32x4 acc[4][4];
#pragma unroll
    for (int i = 0; i < 4; ++i)
#pragma unroll
        for (int j = 0; j < 4; ++j) acc[i][j] = (f32x4)0.f;

    for (int kb = 0; kb < 4; ++kb) {
        // ---- stage A,B tiles (swizzled source, linear LDS dest) ----
#pragma unroll
        for (int i = 0; i < 4; ++i) {
            int L    = i * 256 + t;
            int row  = L >> 3;                    // 0..127
            int slot = (L & 7) ^ (row & 7);       // source slot
            const char* srcA = (const char*)h16 +
                ((size_t)(tm * 128 + row)) * 512 + kb * 128 + slot * 16;
            const char* srcB = (const char*)B +
                ((size_t)(nc0 + row)) * 512 + kb * 128 + slot * 16;
            uint32_t ldsOff = (uint32_t)(i * 256 + (t & 192)) * 16;
            __builtin_amdgcn_global_load_lds((gptr_t)srcA, (lptr_t)(lds + ldsOff), 16, 0, 0);
            __builtin_amdgcn_global_load_lds((gptr_t)srcB, (lptr_t)(lds + 16384 + ldsOff), 16, 0, 0);
        }
        __syncthreads();                          // drains vmcnt before barrier

        // ---- compute ----
#pragma unroll
        for (int ks = 0; ks < 2; ++ks) {
            const int sl = (ks * 4 + g4) ^ l7;    // swizzled read slot
            f16x8 a[4], b[4];
#pragma unroll
            for (int am = 0; am < 4; ++am) {
                int row = wm + am * 16 + r15;
                a[am] = *(const f16x8*)(lds + row * 128 + sl * 16);
            }
#pragma unroll
            for (int bn = 0; bn < 4; ++bn) {
                int row = wn + bn * 16 + r15;
                b[bn] = *(const f16x8*)(lds + 16384 + row * 128 + sl * 16);
            }
#pragma unroll
            for (int am = 0; am < 4; ++am)
#pragma unroll
                for (int bn = 0; bn < 4; ++bn)
                    acc[am][bn] = __builtin_amdgcn_mfma_f32_16x16x32_f16(
                        a[am], b[bn], acc[am][bn], 0, 0, 0);
        }
        if (kb < 3) __syncthreads();              // protect LDS before restage
    }

    // ---- epilogue: C row = (lane>>4)*4 + reg, col = lane&15 ----
#pragma unroll
    for (int am = 0; am < 4; ++am) {
#pragma unroll
        for (int bn = 0; bn < 4; ++bn) {
#pragma unroll
            for (int j = 0; j < 4; ++j) {
                int gm  = tm * 128 + wm + am * 16 + g4 * 4 + j;
                int col = nc0 + wn + bn * 16 + r15;
                if (gm < NN) O[(size_t)gm * 256 + col] = (f16)acc[am][bn][j];
            }
        }
    }
}

// ---------------------------------------------------------------------------
// 2D RoPE in-place on f16 Q,K. One thread per (node, head): 32 dims = 64 B.
// pairs (j, j+8) rotated by freq_x, (16+j, 24+j) by freq_y, j=0..7.
// inv_freq[j] = 10^(-j/2);  angle = coord * 64 * inv_freq.
// ---------------------------------------------------------------------------
__global__ __launch_bounds__(256) void rope16(const float* __restrict__ pos,
                                              f16* __restrict__ Q,
                                              f16* __restrict__ K)
{
    int gid = blockIdx.x * 256 + threadIdx.x;
    if (gid >= NN * 8) return;
    int n = gid >> 3, hd = gid & 7;

    float cx = pos[2 * n] * 64.f;
    float cy = pos[2 * n + 1] * 64.f;
    size_t base = (size_t)n * 256 + hd * 32;

    union U { f16 h[32]; float4 v[4]; } q, k;
#pragma unroll
    for (int i = 0; i < 4; ++i) {
        q.v[i] = ((const float4*)(Q + base))[i];
        k.v[i] = ((const float4*)(K + base))[i];
    }

    const float INVF[8] = {1.f, 0.31622776601683794f, 0.1f, 0.031622776601683794f,
                           0.01f, 0.0031622776601683794f, 0.001f, 0.00031622776601683794f};
#pragma unroll
    for (int j = 0; j < 8; ++j) {
        float sx, cxs, sy, cys;
        __sincosf(cx * INVF[j], &sx, &cxs);
        __sincosf(cy * INVF[j], &sy, &cys);
        float a, b;
        a = (float)q.h[j];      b = (float)q.h[j + 8];
        q.h[j] = (f16)(a * cxs - b * sx);  q.h[j + 8] = (f16)(b * cxs + a * sx);
        a = (float)k.h[j];      b = (float)k.h[j + 8];
        k.h[j] = (f16)(a * cxs - b * sx);  k.h[j + 8] = (f16)(b * cxs + a * sx);
        a = (float)q.h[16 + j]; b = (float)q.h[24 + j];
        q.h[16 + j] = (f16)(a * cys - b * sy);  q.h[24 + j] = (f16)(b * cys + a * sy);
        a = (float)k.h[16 + j]; b = (float)k.h[24 + j];
        k.h[16 + j] = (f16)(a * cys - b * sy);  k.h[24 + j] = (f16)(b * cys + a * sy);
    }

#pragma unroll
    for (int i = 0; i < 4; ++i) {
        ((float4*)(Q + base))[i] = q.v[i];
        ((float4*)(K + base))[i] = k.v[i];
    }
}

// ---------------------------------------------------------------------------
// Edge attention + segment reduce. dst = repeat(arange(N), 16).
// Block 256 thr = 2 nodes x 128 thr; per node: 8 heads x 16 lanes, f16x2/lane.
// 16-lane shfl_xor dot reduce; f32 accumulate; f32 out.
// ---------------------------------------------------------------------------
__global__ __launch_bounds__(256) void edge16(
    const f16* __restrict__ Q, const f16* __restrict__ K, const f16* __restrict__ V,
    const int* __restrict__ src, const int* __restrict__ dst,
    float* __restrict__ out)
{
    const int tid = threadIdx.x;
    const int n   = blockIdx.x * 2 + (tid >> 7);
    const int tl  = tid & 127;
    const int eb  = n * DEG;

    const f16x2* Q2 = (const f16x2*)Q;
    const f16x2* K2 = (const f16x2*)K;
    const f16x2* V2 = (const f16x2*)V;

    const int orow = dst[eb];                  // uniform per node (== n)
    f16x2 q2 = Q2[(size_t)orow * 128 + tl];
    const float qx = (float)q2.x, qy = (float)q2.y;

    float ax = 0.f, ay = 0.f, z = 0.f;
#pragma unroll
    for (int j = 0; j < DEG; ++j) {
        int s = src[eb + j];
        f16x2 k2 = K2[(size_t)s * 128 + tl];
        float p = qx * (float)k2.x + qy * (float)k2.y;
        p += __shfl_xor(p, 8);
        p += __shfl_xor(p, 4);
        p += __shfl_xor(p, 2);
        p += __shfl_xor(p, 1);
        float sc = __expf(fminf(fmaxf(p * 0.17677669529663687f, -5.f), 5.f));
        f16x2 v2 = V2[(size_t)s * 128 + tl];
        ax += sc * (float)v2.x;
        ay += sc * (float)v2.y;
        z  += sc;
    }
    float2 o;
    o.x = ax / z;
    o.y = ay / z;
    *(float2*)(out + (size_t)orow * 256 + tl * 2) = o;
}

// ---------------------------------------------------------------------------
extern "C" void kernel_launch(void* const* d_in, const int* in_sizes, int n_in,
                              void* d_out, int out_size, void* d_ws, size_t ws_size,
                              hipStream_t stream)
{
    const float* h   = (const float*)d_in[0];
    const float* pos = (const float*)d_in[1];
    const float* Wq  = (const float*)d_in[2];
    const float* Wk  = (const float*)d_in[3];
    const float* Wv  = (const float*)d_in[4];
    const int*   src = (const int*)d_in[5];
    const int*   dst = (const int*)d_in[6];
    float* out = (float*)d_out;

    char* w = (char*)d_ws;
    f16* h16 = (f16*)w;                                   // 25,624,576 B
    f16* Wt  = (f16*)(w + 25624576);                      //    393,216 B
    f16* Qb  = (f16*)(w + 26017792);                      // 25,624,576 B
    f16* Kb  = (f16*)(w + 51642368);
    f16* Vb  = (f16*)(w + 77266944);                      // end ~102.9 MB

    conv_h<<<(NPAD * CD / 8 + 255) / 256, 256, 0, stream>>>(h, h16);
    conv_w<<<dim3(256, 3), 256, 0, stream>>>(Wq, Wk, Wv, Wt);
    gemm16<<<dim3(391, 2, 3), 256, 0, stream>>>(h16, Wt, Qb, Kb, Vb);
    rope16<<<(NN * 8 + 255) / 256, 256, 0, stream>>>(pos, Qb, Kb);
    edge16<<<25000, 256, 0, stream>>>(Qb, Kb, Vb, src, dst, out);
}